// Round 5
// baseline (25979.102 us; speedup 1.0000x reference)
//
#include <hip/hip_runtime.h>
#include <stdint.h>

// Farthest point sampling, pointops semantics.
// B=8 batches, n=65536, stride=64 -> m=1024 samples/batch.
// 32 WGs per batch, coords+dists register-resident.
// Per-step global argmax: each WG does ONE packed-key device atomicMax into a
// parity-double-buffered key cell + a release fetch_add on a monotone arrival
// counter. Waves poll the counter (acquire), then read key[it&1]. Winner
// coords are re-loaded from the read-only input (L2-cached).
//
// Race-safety of the parity cell: key[it&1] can only be overwritten by a
// publish for it+2, which requires counter >= 32*(it+1), which requires every
// WG to have published it+1, which each WG does only after its __syncthreads
// -- i.e. after ALL its waves finished reading key(it). Stale it-2 keys lose
// fetch_max automatically (it field in top bits).

#define G    32      // workgroups per batch
#define BS   256     // threads per workgroup
#define PPT  8       // points per thread (G*BS*PPT == n)

typedef unsigned long long u64;
typedef unsigned int u32;

// key layout: [57:48]=it  [47:16]=float bits of best dist (nonneg)  [15:0]=0xFFFF-idx
// - it in top bits: later iterations always beat stale keys (no reset needed)
// - nonneg IEEE floats compare like their bit patterns
// - 0xFFFF-idx: bigger wins => smaller idx wins ties (numpy argmax semantics)

__global__ __launch_bounds__(BS, 1)
void fps_amax(const float* __restrict__ p, int n, int m,
              u64* __restrict__ comm,
              float* __restrict__ out_np, float* __restrict__ out_no,
              float* __restrict__ out_idx)
{
#pragma clang fp contract(off)
    const int bg = blockIdx.x;
    const int b  = bg / G;
    const int g  = bg % G;
    const int t  = threadIdx.x;
    const int lane = t & 63;
    const int w    = t >> 6;
    const int gbase  = b * n;          // global point base of this batch
    const int wgbase = g * (BS * PPT); // batch-local base of this WG's points

    __shared__ float s_val[BS / 64];
    __shared__ int   s_idx[BS / 64];

    // per-batch 256B region: key0 @ +0, key1 @ +64B, counter @ +128B
    u64* base64 = comm + (size_t)b * 32;
    u64* key0 = base64;
    u64* key1 = base64 + 8;
    u32* cntp = (u32*)(base64 + 16);

    // ---- load this WG's 2048 points into registers (one-time) ----
    float px[PPT], py[PPT], pz[PPT], dist[PPT];
    {
        const float* pb = p + 3ull * (u32)(gbase + wgbase + t * PPT);
#pragma unroll
        for (int j = 0; j < PPT; ++j) {
            px[j] = pb[3 * j + 0];
            py[j] = pb[3 * j + 1];
            pz[j] = pb[3 * j + 2];
            dist[j] = 1e10f;
        }
    }

    // first query = point 0 of the batch
    float qx = p[3ull * (u32)gbase + 0];
    float qy = p[3ull * (u32)gbase + 1];
    float qz = p[3ull * (u32)gbase + 2];

    if (g == 0 && t == 0) {
        out_idx[(size_t)b * m] = (float)gbase;
        out_np[(size_t)(b * m) * 3 + 0] = qx;
        out_np[(size_t)(b * m) * 3 + 1] = qy;
        out_np[(size_t)(b * m) * 3 + 2] = qz;
        out_no[b] = (float)((b + 1) * m);
    }

    for (int it = 1; it < m; ++it) {
        // ---- local distance update + per-thread argmax (ids ascending in j) ----
        float best = -1.0f;
        int   bj   = 0;
#pragma unroll
        for (int j = 0; j < PPT; ++j) {
            float dx = px[j] - qx;
            float dy = py[j] - qy;
            float dz = pz[j] - qz;
            float d  = dx * dx + dy * dy + dz * dz;   // contract off: left-assoc
            float nd = fminf(dist[j], d);
            dist[j] = nd;
            if (nd > best) { best = nd; bj = j; }     // strict > keeps earliest
        }
        int bidx = wgbase + t * PPT + bj;             // batch-local winner idx

        // ---- wave argmax (64 lanes, ids ascend with lane) ----
#pragma unroll
        for (int off = 1; off < 64; off <<= 1) {
            float ov = __shfl_xor(best, off);
            int   oi = __shfl_xor(bidx, off);
            if (ov > best || (ov == best && oi < bidx)) { best = ov; bidx = oi; }
        }
        if (lane == 0) { s_val[w] = best; s_idx[w] = bidx; }
        __syncthreads();   // the only barrier per step

        u64* keyp = (it & 1) ? key1 : key0;

        // ---- t0: cross-wave reduce, publish packed key, signal arrival ----
        if (t == 0) {
            float v = -1.0f; int ix = 0x7fffffff;
#pragma unroll
            for (int ww = 0; ww < BS / 64; ++ww) {
                if (s_val[ww] > v || (s_val[ww] == v && s_idx[ww] < ix)) {
                    v = s_val[ww]; ix = s_idx[ww];
                }
            }
            u64 k = ((u64)(u32)it << 48)
                  | ((u64)(u32)__float_as_uint(v) << 16)
                  | (u64)(u32)(0xFFFF - ix);
            __hip_atomic_fetch_max(keyp, k, __ATOMIC_RELAXED,
                                   __HIP_MEMORY_SCOPE_AGENT);
            // RELEASE: key max completes before the arrival is visible
            __hip_atomic_fetch_add(cntp, 1u, __ATOMIC_RELEASE,
                                   __HIP_MEMORY_SCOPE_AGENT);
        }

        // ---- every wave: lane0 polls arrival counter, reads this parity's key ----
        int kidx = 0;
        if (lane == 0) {
            u32 target = (u32)(G * it);   // counter is monotone: no reset needed
            u32 c;
            do {
                c = __hip_atomic_load(cntp, __ATOMIC_ACQUIRE,
                                      __HIP_MEMORY_SCOPE_AGENT);
            } while (c < target);
            u64 kk = __hip_atomic_load(keyp, __ATOMIC_RELAXED,
                                       __HIP_MEMORY_SCOPE_AGENT);
            kidx = 0xFFFF - (int)(kk & 0xFFFF);
        }
        kidx = __shfl(kidx, 0);

        // winner coords from the read-only input (L2-cached, coherence-free)
        const float* wp = p + 3ull * (u32)(gbase + kidx);
        qx = wp[0]; qy = wp[1]; qz = wp[2];

        if (g == 0 && t == 0) {
            out_idx[(size_t)b * m + it] = (float)(gbase + kidx);
            out_np[(size_t)(b * m + it) * 3 + 0] = qx;
            out_np[(size_t)(b * m + it) * 3 + 1] = qy;
            out_np[(size_t)(b * m + it) * 3 + 2] = qz;
        }
    }
}

extern "C" void kernel_launch(void* const* d_in, const int* in_sizes, int n_in,
                              void* d_out, int out_size, void* d_ws, size_t ws_size,
                              hipStream_t stream) {
    const float* p = (const float*)d_in[0];
    int N = in_sizes[0] / 3;           // 524288
    int B = in_sizes[1];               // 8
    int n = N / B;                     // 65536
    int m = (out_size / B - 1) / 4;    // 1024

    float* out_np  = (float*)d_out;
    float* out_no  = out_np + (size_t)B * m * 3;
    float* out_idx = out_no + B;

    u64* comm = (u64*)d_ws;
    // clear key/counter cells every launch (graph-safe)
    hipMemsetAsync(d_ws, 0, (size_t)B * 256, stream);

    fps_amax<<<B * G, BS, 0, stream>>>(p, n, m, comm, out_np, out_no, out_idx);
}

// Round 6
// 3049.034 us; speedup vs baseline: 8.5204x; 8.5204x over previous
//
#include <hip/hip_runtime.h>
#include <stdint.h>

// Farthest point sampling, pointops semantics.
// B=8 batches, n=65536, stride=64 -> m=1024 samples/batch.
// 8 WGs per batch, 32 pts/thread pinned in VGPRs (asm barrier stops the
// compiler rematerializing them from memory each step -- round-5 bug).
// Per-step global argmax: each WG's t0 does one packed-key device atomicMax
// into a parity-buffered key cell + release fetch_add on a monotone arrival
// counter; t0 then polls the counter with RELAXED agent loads (no acquire ->
// no buffer_inv cache-thrash) + s_sleep, reads the key, broadcasts via LDS.
//
// Parity-cell safety: key[it&1] can only be overwritten by a publish for
// it+2, which needs cnt >= 8*(it+1), which needs every WG past step it+1's
// publish -- and each WG's (sole) reader of key(it) is t0 itself, which read
// it before that WG could publish it+1. Stale it-2 keys lose fetch_max (it
// field in top bits). Counter is monotone: no reset, no replay staleness
// (comm region memset every launch).

#define G    8       // workgroups per batch
#define BS   256     // threads per workgroup
#define PPT  32      // points per thread (G*BS*PPT == n)

typedef unsigned long long u64;
typedef unsigned int u32;

// key layout: [57:48]=it  [47:16]=float bits of best dist (nonneg)  [15:0]=0xFFFF-idx
// nonneg IEEE floats compare like their bit patterns; bigger (0xFFFF-idx)
// wins => smaller idx wins ties (numpy argmax semantics).

__global__ __launch_bounds__(BS, 1)
void fps_amax(const float* __restrict__ p, int n, int m,
              u64* __restrict__ comm,
              float* __restrict__ out_np, float* __restrict__ out_no,
              float* __restrict__ out_idx)
{
#pragma clang fp contract(off)
    const int bg = blockIdx.x;
    const int b  = bg / G;
    const int g  = bg % G;
    const int t  = threadIdx.x;
    const int lane = t & 63;
    const int w    = t >> 6;
    const int gbase  = b * n;          // global point base of this batch
    const int wgbase = g * (BS * PPT); // batch-local base of this WG's points

    __shared__ float s_val[BS / 64];
    __shared__ int   s_idx[BS / 64];
    __shared__ int   s_k;

    // per-batch comm (1 KiB stride): key0 @ +0, key1 @ +256B, cnt @ +512B
    u64* base64 = comm + (size_t)b * 128;
    u64* key0 = base64;
    u64* key1 = base64 + 32;
    u32* cntp = (u32*)(base64 + 64);

    // ---- load this WG's 8192 points into registers (one-time), then PIN ----
    float px[PPT], py[PPT], pz[PPT], dist[PPT];
    {
        const float* pb = p + 3ull * (u32)(gbase + wgbase + t * PPT);
#pragma unroll
        for (int j = 0; j < PPT; ++j) {
            px[j] = pb[3 * j + 0];
            py[j] = pb[3 * j + 1];
            pz[j] = pb[3 * j + 2];
            dist[j] = 1e10f;
        }
#pragma unroll
        for (int j = 0; j < PPT; ++j) {
            // opaque register barrier: compiler can no longer re-load these
            // from p[] inside the main loop (round-5 perf bug: VGPR=28).
            asm volatile("" : "+v"(px[j]), "+v"(py[j]), "+v"(pz[j]));
        }
    }

    // first query = point 0 of the batch
    float qx = p[3ull * (u32)gbase + 0];
    float qy = p[3ull * (u32)gbase + 1];
    float qz = p[3ull * (u32)gbase + 2];

    if (g == 0 && t == 0) {
        out_idx[(size_t)b * m] = (float)gbase;
        out_np[(size_t)(b * m) * 3 + 0] = qx;
        out_np[(size_t)(b * m) * 3 + 1] = qy;
        out_np[(size_t)(b * m) * 3 + 2] = qz;
        out_no[b] = (float)((b + 1) * m);
    }

    for (int it = 1; it < m; ++it) {
        // ---- local distance update + per-thread argmax (ids ascending in j) ----
        float best = -1.0f;
        int   bj   = 0;
#pragma unroll
        for (int j = 0; j < PPT; ++j) {
            float dx = px[j] - qx;
            float dy = py[j] - qy;
            float dz = pz[j] - qz;
            float d  = dx * dx + dy * dy + dz * dz;   // contract off: left-assoc
            float nd = fminf(dist[j], d);
            dist[j] = nd;
            if (nd > best) { best = nd; bj = j; }     // strict > keeps earliest
        }
        int bidx = wgbase + t * PPT + bj;             // batch-local winner idx

        // ---- wave argmax (64 lanes, ids ascend with lane) ----
#pragma unroll
        for (int off = 1; off < 64; off <<= 1) {
            float ov = __shfl_xor(best, off);
            int   oi = __shfl_xor(bidx, off);
            if (ov > best || (ov == best && oi < bidx)) { best = ov; bidx = oi; }
        }
        if (lane == 0) { s_val[w] = best; s_idx[w] = bidx; }
        __syncthreads();

        u64* keyp = (it & 1) ? key1 : key0;

        // ---- t0: reduce, publish, poll (relaxed only), broadcast ----
        if (t == 0) {
            float v = -1.0f; int ix = 0x7fffffff;
#pragma unroll
            for (int ww = 0; ww < BS / 64; ++ww) {
                if (s_val[ww] > v || (s_val[ww] == v && s_idx[ww] < ix)) {
                    v = s_val[ww]; ix = s_idx[ww];
                }
            }
            u64 k = ((u64)(u32)it << 48)
                  | ((u64)(u32)__float_as_uint(v) << 16)
                  | (u64)(u32)(0xFFFF - ix);
            __hip_atomic_fetch_max(keyp, k, __ATOMIC_RELAXED,
                                   __HIP_MEMORY_SCOPE_AGENT);
            // RELEASE: the key max is applied at the coherence point before
            // this arrival increment is observable there.
            __hip_atomic_fetch_add(cntp, 1u, __ATOMIC_RELEASE,
                                   __HIP_MEMORY_SCOPE_AGENT);

            u32 target = (u32)(G * it);   // monotone counter
            u32 c = __hip_atomic_load(cntp, __ATOMIC_RELAXED,
                                      __HIP_MEMORY_SCOPE_AGENT);
            while (c < target) {
                __builtin_amdgcn_s_sleep(1);
                c = __hip_atomic_load(cntp, __ATOMIC_RELAXED,
                                      __HIP_MEMORY_SCOPE_AGENT);
            }
            // relaxed sc1 load, issued after the poll resolved: sees all maxes
            u64 kk = __hip_atomic_load(keyp, __ATOMIC_RELAXED,
                                       __HIP_MEMORY_SCOPE_AGENT);
            s_k = 0xFFFF - (int)(kk & 0xFFFF);
        }
        __syncthreads();
        int kidx = s_k;

        // winner coords from the read-only input (caches stay warm: no
        // invalidating ops anywhere in the loop)
        const float* wp = p + 3ull * (u32)(gbase + kidx);
        qx = wp[0]; qy = wp[1]; qz = wp[2];

        if (g == 0 && t == 0) {
            out_idx[(size_t)b * m + it] = (float)(gbase + kidx);
            out_np[(size_t)(b * m + it) * 3 + 0] = qx;
            out_np[(size_t)(b * m + it) * 3 + 1] = qy;
            out_np[(size_t)(b * m + it) * 3 + 2] = qz;
        }
    }
}

extern "C" void kernel_launch(void* const* d_in, const int* in_sizes, int n_in,
                              void* d_out, int out_size, void* d_ws, size_t ws_size,
                              hipStream_t stream) {
    const float* p = (const float*)d_in[0];
    int N = in_sizes[0] / 3;           // 524288
    int B = in_sizes[1];               // 8
    int n = N / B;                     // 65536
    int m = (out_size / B - 1) / 4;    // 1024

    float* out_np  = (float*)d_out;
    float* out_no  = out_np + (size_t)B * m * 3;
    float* out_idx = out_no + B;

    u64* comm = (u64*)d_ws;
    // clear key/counter cells every launch (graph-safe)
    hipMemsetAsync(d_ws, 0, (size_t)B * 1024, stream);

    fps_amax<<<B * G, BS, 0, stream>>>(p, n, m, comm, out_np, out_no, out_idx);
}